// Round 5
// baseline (337.014 us; speedup 1.0000x reference)
//
#include <hip/hip_runtime.h>

#define NNODES 100000
#define NEDGES 1600000
#define BN_EPS 1e-5f
#define L2_EPS 1e-12f

#define BKT_SHIFT 9
#define BKT_SIZE  512
#define NBKT      196            // ceil(100000/512)
#define CHUNK     4096
#define NBLK_E    391            // ceil(1600000/4096)

// ---------------------------------------------------------------------------
// Pass 1: per-block bucket histogram (LDS) -> dense blk_hist. No global
// atomics. Block 0 also zeroes the BN stats accumulators (read 5 kernels later).
__global__ void hist_kernel(const int* __restrict__ dst,
                            int* __restrict__ blk_hist, float* __restrict__ stats) {
    __shared__ int h[NBKT];
    for (int i = threadIdx.x; i < NBKT; i += blockDim.x) h[i] = 0;
    if (blockIdx.x == 0 && threadIdx.x < 128) {
        stats[threadIdx.x] = 0.0f;
        stats[threadIdx.x + 128] = 0.0f;
        stats[threadIdx.x + 256] = 0.0f;
    }
    __syncthreads();
    int base = blockIdx.x * CHUNK;
    int end  = min(base + CHUNK, NEDGES);
    for (int e = base + threadIdx.x; e < end; e += blockDim.x)
        atomicAdd(&h[dst[e] >> BKT_SHIFT], 1);
    __syncthreads();
    for (int i = threadIdx.x; i < NBKT; i += blockDim.x)
        blk_hist[blockIdx.x * NBKT + i] = h[i];
}

// Per-bucket exclusive scan across blocks (relative to bucket start) + emits
// bucket totals as a by-product (inclusive scan tail).
__global__ void scan_blocks(const int* __restrict__ blk_hist,
                            int* __restrict__ blk_off, int* __restrict__ bucket_total) {
    __shared__ int tmp[512];
    int b = blockIdx.x;
    int i = threadIdx.x;
    int v = (i < NBLK_E) ? blk_hist[i * NBKT + b] : 0;
    tmp[i] = v;
    __syncthreads();
    for (int off = 1; off < 512; off <<= 1) {
        int t = (i >= off) ? tmp[i - off] : 0;
        __syncthreads();
        tmp[i] += t;
        __syncthreads();
    }
    if (i < NBLK_E) blk_off[i * NBKT + b] = tmp[i] - v;   // bucket-relative
    if (i == 511) bucket_total[b] = tmp[511];
}

// Exclusive scan of bucket totals -> bucket_base[NBKT+1]
__global__ void scan_buckets(const int* __restrict__ bucket_total, int* __restrict__ bucket_base) {
    __shared__ int tmp[256];
    int v = (threadIdx.x < NBKT) ? bucket_total[threadIdx.x] : 0;
    tmp[threadIdx.x] = v;
    __syncthreads();
    for (int off = 1; off < 256; off <<= 1) {
        int t = (threadIdx.x >= off) ? tmp[threadIdx.x - off] : 0;
        __syncthreads();
        tmp[threadIdx.x] += t;
        __syncthreads();
    }
    if (threadIdx.x < NBKT) bucket_base[threadIdx.x] = tmp[threadIdx.x] - v;
    if (threadIdx.x == 0) bucket_base[NBKT] = NEDGES;
}

// Pass 2: scatter edges into bucket segments (packed dst_local<<23 | src).
__global__ void bucket_scatter(const int* __restrict__ src, const int* __restrict__ dst,
                               const int* __restrict__ blk_off, const int* __restrict__ bucket_base,
                               unsigned int* __restrict__ staged) {
    __shared__ int cur[NBKT];
    for (int i = threadIdx.x; i < NBKT; i += blockDim.x)
        cur[i] = blk_off[blockIdx.x * NBKT + i] + bucket_base[i];
    __syncthreads();
    int base = blockIdx.x * CHUNK;
    int end  = min(base + CHUNK, NEDGES);
    for (int e = base + threadIdx.x; e < end; e += blockDim.x) {
        int d = dst[e];
        int b = d >> BKT_SHIFT;
        int p = atomicAdd(&cur[b], 1);          // LDS atomic only
        staged[p] = ((unsigned)(d & (BKT_SIZE - 1)) << 23) | (unsigned)src[e];
    }
}

// Pass 3: one block per bucket -> exact CSR (row_ptr + node-sorted col).
__global__ void csr_finalize(const unsigned int* __restrict__ staged,
                             const int* __restrict__ bucket_base,
                             int* __restrict__ row_ptr, int* __restrict__ col) {
    __shared__ int nh[BKT_SIZE];
    __shared__ int cur[BKT_SIZE];
    int b = blockIdx.x;
    int beg = bucket_base[b], end = bucket_base[b + 1];

    nh[threadIdx.x] = 0;
    __syncthreads();
    for (int e = beg + threadIdx.x; e < end; e += blockDim.x)
        atomicAdd(&nh[staged[e] >> 23], 1);
    __syncthreads();

    int v = nh[threadIdx.x];
    cur[threadIdx.x] = v;
    __syncthreads();
    for (int off = 1; off < 512; off <<= 1) {
        int t = (threadIdx.x >= off) ? cur[threadIdx.x - off] : 0;
        __syncthreads();
        cur[threadIdx.x] += t;
        __syncthreads();
    }
    int excl = cur[threadIdx.x] - v;

    int node = b * BKT_SIZE + threadIdx.x;
    if (node < NNODES) row_ptr[node] = beg + excl;
    if (b == 0 && threadIdx.x == 0) row_ptr[NNODES] = NEDGES;
    __syncthreads();
    cur[threadIdx.x] = excl;
    __syncthreads();

    for (int e = beg + threadIdx.x; e < end; e += blockDim.x) {
        unsigned pk = staged[e];
        int l = (int)(pk >> 23);
        int p = atomicAdd(&cur[l], 1);          // LDS atomic only
        col[beg + p] = (int)(pk & 0x7FFFFF);
    }
}

// ---------------------------------------------------------------------------
// Vector row load: float4 chunks, then float2, then scalar. Base must be
// 8/16B-aligned per the chosen stride (guaranteed by SI choices below).
template<int CI>
__device__ __forceinline__ void load_row(const float* __restrict__ p, float* r) {
    constexpr int N4 = CI / 4;
#pragma unroll
    for (int i = 0; i < N4; i++) {
        float4 v = ((const float4*)p)[i];
        r[4*i] = v.x; r[4*i+1] = v.y; r[4*i+2] = v.z; r[4*i+3] = v.w;
    }
    if constexpr ((CI % 4) >= 2) {
        float2 v = ((const float2*)(p + 4 * N4))[0];
        r[4*N4] = v.x; r[4*N4+1] = v.y;
    }
    if constexpr ((CI % 2) == 1) r[CI - 1] = p[CI - 1];
}

// ---------------------------------------------------------------------------
// Fused layer, lane-group parallel (G lanes/node). Input stride SI, output
// stride SO. If IN_AFFINE: derive prev-BN affine from raw stats in-block.
template<int CI, int SI, int CO, int SO, int G, bool IN_AFFINE, bool DO_STATS>
__global__ void layer_kernel(const int* __restrict__ row_ptr, const int* __restrict__ col,
                             const float* __restrict__ h,
                             const float* __restrict__ ssum_in, const float* __restrict__ ssq_in,
                             const float* __restrict__ g_in, const float* __restrict__ b_in,
                             const float* __restrict__ wl, const float* __restrict__ bl,
                             const float* __restrict__ wr,
                             float* __restrict__ y,
                             float* __restrict__ stat_sum, float* __restrict__ stat_sq) {
    constexpr int NPB = 256 / G;             // nodes per block
    constexpr int OPL = (CO + G - 1) / G;    // outputs per lane

    __shared__ float sWl[CO * CI];
    __shared__ float sWr[CO * CI];
    __shared__ float sBl[CO];
    __shared__ float sSc[CI];
    __shared__ float sSh[CI];
    __shared__ float red_sum[CO];
    __shared__ float red_sq[CO];

    for (int i = threadIdx.x; i < CO * CI; i += blockDim.x) {
        sWl[i] = wl[i];
        sWr[i] = wr[i];
    }
    if (threadIdx.x < CO) {
        sBl[threadIdx.x] = bl[threadIdx.x];
        if (DO_STATS) { red_sum[threadIdx.x] = 0.0f; red_sq[threadIdx.x] = 0.0f; }
    }
    if (IN_AFFINE && threadIdx.x < CI) {
        float m  = ssum_in[threadIdx.x] * (1.0f / NNODES);
        float vv = ssq_in[threadIdx.x] * (1.0f / NNODES) - m * m;
        float s  = g_in[threadIdx.x] / sqrtf(vv + BN_EPS);
        sSc[threadIdx.x] = s;
        sSh[threadIdx.x] = b_in[threadIdx.x] - m * s;
    }
    __syncthreads();

    int node = blockIdx.x * NPB + (threadIdx.x / G);
    int g    = threadIdx.x & (G - 1);
    bool valid = node < NNODES;

    float acc[CI];
#pragma unroll
    for (int c = 0; c < CI; c++) acc[c] = 0.0f;

    int beg = 0, end = 0;
    if (valid) {
        beg = row_ptr[node];
        end = row_ptr[node + 1];
        int j = beg + g;
        for (; j + G < end; j += 2 * G) {       // 2 rows in flight per lane
            int i0 = col[j], i1 = col[j + G];
            float r0[CI], r1[CI];
            load_row<CI>(h + (long)i0 * SI, r0);
            load_row<CI>(h + (long)i1 * SI, r1);
#pragma unroll
            for (int c = 0; c < CI; c++) acc[c] += r0[c] + r1[c];
        }
        if (j < end) {
            float r0[CI];
            load_row<CI>(h + (long)col[j] * SI, r0);
#pragma unroll
            for (int c = 0; c < CI; c++) acc[c] += r0[c];
        }
    }

    // butterfly: all G lanes end with the full neighbor sum
#pragma unroll
    for (int m = 1; m < G; m <<= 1)
#pragma unroll
        for (int c = 0; c < CI; c++) acc[c] += __shfl_xor(acc[c], m);

    float out[OPL];
    float nrm2 = 0.0f;
    if (valid) {
        float ic = 1.0f / fmaxf((float)(end - beg), 1.0f);
        float xin[CI];
        load_row<CI>(h + (long)node * SI, xin);
        float agg[CI];
#pragma unroll
        for (int c = 0; c < CI; c++) {
            float a  = acc[c] * ic;
            float xv = xin[c];
            if (IN_AFFINE) {
                a  = a  * sSc[c] + sSh[c];
                xv = xv * sSc[c] + sSh[c];
            }
            agg[c] = a;
            xin[c] = xv;
        }
#pragma unroll
        for (int k = 0; k < OPL; k++) {
            int o = g * OPL + k;
            float v = 0.0f;
            if (o < CO) {
                v = sBl[o];
#pragma unroll
                for (int c = 0; c < CI; c++)
                    v += sWl[o * CI + c] * agg[c] + sWr[o * CI + c] * xin[c];
            }
            out[k] = v;
            nrm2 += v * v;
        }
    }
#pragma unroll
    for (int m = 1; m < G; m <<= 1) nrm2 += __shfl_xor(nrm2, m);

    if (valid) {
        float inv_nrm = 1.0f / fmaxf(sqrtf(nrm2), L2_EPS);
#pragma unroll
        for (int k = 0; k < OPL; k++) {
            int o = g * OPL + k;
            if (o < CO) {
                float v = fmaxf(out[k] * inv_nrm, 0.0f);   // L2 norm + ReLU
                y[(long)node * SO + o] = v;
                if (DO_STATS) {
                    atomicAdd(&red_sum[o], v);
                    atomicAdd(&red_sq[o], v * v);
                }
            }
        }
    }

    if (DO_STATS) {
        __syncthreads();
        if (threadIdx.x < CO) {
            atomicAdd(&stat_sum[threadIdx.x], red_sum[threadIdx.x]);
            atomicAdd(&stat_sq[threadIdx.x], red_sq[threadIdx.x]);
        }
    }
}

// ---------------------------------------------------------------------------
extern "C" void kernel_launch(void* const* d_in, const int* in_sizes, int n_in,
                              void* d_out, int out_size, void* d_ws, size_t ws_size,
                              hipStream_t stream) {
    const float* x   = (const float*)d_in[0];
    const int*   ei  = (const int*)d_in[1];
    const int*   src = ei;
    const int*   dst = ei + NEDGES;

    const float* w1l = (const float*)d_in[2];
    const float* b1l = (const float*)d_in[3];
    const float* w1r = (const float*)d_in[4];
    const float* w2l = (const float*)d_in[5];
    const float* b2l = (const float*)d_in[6];
    const float* w2r = (const float*)d_in[7];
    const float* w3l = (const float*)d_in[8];
    const float* b3l = (const float*)d_in[9];
    const float* w3r = (const float*)d_in[10];
    const float* w4l = (const float*)d_in[11];
    const float* b4l = (const float*)d_in[12];
    const float* w4r = (const float*)d_in[13];
    const float* g1  = (const float*)d_in[14];
    const float* be1 = (const float*)d_in[15];
    const float* g2  = (const float*)d_in[16];
    const float* be2 = (const float*)d_in[17];
    const float* g3  = (const float*)d_in[18];
    const float* be3 = (const float*)d_in[19];

    char* w = (char*)d_ws;
    int* blk_hist     = (int*)w;  w += NBLK_E * NBKT * 4;
    int* blk_off      = (int*)w;  w += NBLK_E * NBKT * 4;
    int* bucket_total = (int*)w;  w += 256 * 4;
    int* bucket_base  = (int*)w;  w += 256 * 4;
    int* row_ptr      = (int*)w;  w += (NNODES + 8) * 4;
    int* col          = (int*)w;  w += NEDGES * 4;
    float* hA         = (float*)w; w += NNODES * 16 * 4;   // stride-8 use; sized 16 for reuse
    float* hB         = (float*)w; w += NNODES * 16 * 4;   // aliased by staged (6.4 MB)
    float* stats      = (float*)w; w += 3 * 128 * 4;
    unsigned int* staged = (unsigned int*)hB;  // dead before hB is written

    float* ssum1 = stats + 0 * 128, *ssq1 = ssum1 + 32;
    float* ssum2 = stats + 1 * 128, *ssq2 = ssum2 + 32;
    float* ssum3 = stats + 2 * 128, *ssq3 = ssum3 + 32;

    // atomic-free CSR build (no memsets: stats zeroed in hist, totals from scan)
    hist_kernel   <<<NBLK_E, 256, 0, stream>>>(dst, blk_hist, stats);
    scan_blocks   <<<NBKT, 512, 0, stream>>>(blk_hist, blk_off, bucket_total);
    scan_buckets  <<<1, 256, 0, stream>>>(bucket_total, bucket_base);
    bucket_scatter<<<NBLK_E, 256, 0, stream>>>(src, dst, blk_off, bucket_base, staged);
    csr_finalize  <<<NBKT, 512, 0, stream>>>(staged, bucket_base, row_ptr, col);

    // layer 1: 4 -> 6 (stride 4 -> 8), G=8, +stats
    layer_kernel<4, 4, 6, 8, 8, false, true><<<(NNODES * 8 + 255) / 256, 256, 0, stream>>>(
        row_ptr, col, x, nullptr, nullptr, nullptr, nullptr,
        w1l, b1l, w1r, hA, ssum1, ssq1);

    // layer 2: 6 -> 8 (stride 8 -> 8), G=8, BN1 derived in-block, +stats
    layer_kernel<6, 8, 8, 8, 8, true, true><<<(NNODES * 8 + 255) / 256, 256, 0, stream>>>(
        row_ptr, col, hA, ssum1, ssq1, g1, be1,
        w2l, b2l, w2r, hB, ssum2, ssq2);

    // layer 3: 8 -> 16 (stride 8 -> 16), G=8, BN2 derived, +stats
    layer_kernel<8, 8, 16, 16, 8, true, true><<<(NNODES * 8 + 255) / 256, 256, 0, stream>>>(
        row_ptr, col, hB, ssum2, ssq2, g2, be2,
        w3l, b3l, w3r, hA, ssum3, ssq3);

    // layer 4: 16 -> 32 (stride 16 -> 32), G=16, BN3 derived, ReLU -> d_out
    layer_kernel<16, 16, 32, 32, 16, true, false><<<(NNODES * 16 + 255) / 256, 256, 0, stream>>>(
        row_ptr, col, hA, ssum3, ssq3, g3, be3,
        w4l, b4l, w4r, (float*)d_out, nullptr, nullptr);
}

// Round 6
// 276.357 us; speedup vs baseline: 1.2195x; 1.2195x over previous
//
#include <hip/hip_runtime.h>

#define NNODES 100000
#define NEDGES 1600000
#define BN_EPS 1e-5f
#define L2_EPS 1e-12f

#define BKT_SHIFT 9
#define BKT_SIZE  512
#define NBKT      196            // ceil(100000/512)
#define CHUNK     4096
#define NBLK_E    391            // ceil(1600000/4096)

// ---------------------------------------------------------------------------
// Pass 1: per-block bucket histogram (LDS) -> dense blk_hist. No global
// atomics. Block 0 also zeroes the BN stats accumulators.
__global__ void hist_kernel(const int* __restrict__ dst,
                            int* __restrict__ blk_hist, float* __restrict__ stats) {
    __shared__ int h[NBKT];
    for (int i = threadIdx.x; i < NBKT; i += blockDim.x) h[i] = 0;
    if (blockIdx.x == 0 && threadIdx.x < 128) {
        stats[threadIdx.x] = 0.0f;
        stats[threadIdx.x + 128] = 0.0f;
        stats[threadIdx.x + 256] = 0.0f;
    }
    __syncthreads();
    int base = blockIdx.x * CHUNK;
    int end  = min(base + CHUNK, NEDGES);
    for (int e = base + threadIdx.x; e < end; e += blockDim.x)
        atomicAdd(&h[dst[e] >> BKT_SHIFT], 1);
    __syncthreads();
    for (int i = threadIdx.x; i < NBKT; i += blockDim.x)
        blk_hist[blockIdx.x * NBKT + i] = h[i];
}

// Per-bucket exclusive scan across blocks + bucket totals as by-product.
__global__ void scan_blocks(const int* __restrict__ blk_hist,
                            int* __restrict__ blk_off, int* __restrict__ bucket_total) {
    __shared__ int tmp[512];
    int b = blockIdx.x;
    int i = threadIdx.x;
    int v = (i < NBLK_E) ? blk_hist[i * NBKT + b] : 0;
    tmp[i] = v;
    __syncthreads();
    for (int off = 1; off < 512; off <<= 1) {
        int t = (i >= off) ? tmp[i - off] : 0;
        __syncthreads();
        tmp[i] += t;
        __syncthreads();
    }
    if (i < NBLK_E) blk_off[i * NBKT + b] = tmp[i] - v;   // bucket-relative
    if (i == 511) bucket_total[b] = tmp[511];
}

// Exclusive scan of bucket totals -> bucket_base[NBKT+1]
__global__ void scan_buckets(const int* __restrict__ bucket_total, int* __restrict__ bucket_base) {
    __shared__ int tmp[256];
    int v = (threadIdx.x < NBKT) ? bucket_total[threadIdx.x] : 0;
    tmp[threadIdx.x] = v;
    __syncthreads();
    for (int off = 1; off < 256; off <<= 1) {
        int t = (threadIdx.x >= off) ? tmp[threadIdx.x - off] : 0;
        __syncthreads();
        tmp[threadIdx.x] += t;
        __syncthreads();
    }
    if (threadIdx.x < NBKT) bucket_base[threadIdx.x] = tmp[threadIdx.x] - v;
    if (threadIdx.x == 0) bucket_base[NBKT] = NEDGES;
}

// Pass 2: scatter edges into bucket segments (packed dst_local<<23 | src).
__global__ void bucket_scatter(const int* __restrict__ src, const int* __restrict__ dst,
                               const int* __restrict__ blk_off, const int* __restrict__ bucket_base,
                               unsigned int* __restrict__ staged) {
    __shared__ int cur[NBKT];
    for (int i = threadIdx.x; i < NBKT; i += blockDim.x)
        cur[i] = blk_off[blockIdx.x * NBKT + i] + bucket_base[i];
    __syncthreads();
    int base = blockIdx.x * CHUNK;
    int end  = min(base + CHUNK, NEDGES);
    for (int e = base + threadIdx.x; e < end; e += blockDim.x) {
        int d = dst[e];
        int b = d >> BKT_SHIFT;
        int p = atomicAdd(&cur[b], 1);          // LDS atomic only
        staged[p] = ((unsigned)(d & (BKT_SIZE - 1)) << 23) | (unsigned)src[e];
    }
}

// Pass 3: one block per bucket -> exact CSR (row_ptr + node-sorted col).
__global__ void csr_finalize(const unsigned int* __restrict__ staged,
                             const int* __restrict__ bucket_base,
                             int* __restrict__ row_ptr, int* __restrict__ col) {
    __shared__ int nh[BKT_SIZE];
    __shared__ int cur[BKT_SIZE];
    int b = blockIdx.x;
    int beg = bucket_base[b], end = bucket_base[b + 1];

    nh[threadIdx.x] = 0;
    __syncthreads();
    for (int e = beg + threadIdx.x; e < end; e += blockDim.x)
        atomicAdd(&nh[staged[e] >> 23], 1);
    __syncthreads();

    int v = nh[threadIdx.x];
    cur[threadIdx.x] = v;
    __syncthreads();
    for (int off = 1; off < 512; off <<= 1) {
        int t = (threadIdx.x >= off) ? cur[threadIdx.x - off] : 0;
        __syncthreads();
        cur[threadIdx.x] += t;
        __syncthreads();
    }
    int excl = cur[threadIdx.x] - v;

    int node = b * BKT_SIZE + threadIdx.x;
    if (node < NNODES) row_ptr[node] = beg + excl;
    if (b == 0 && threadIdx.x == 0) row_ptr[NNODES] = NEDGES;
    __syncthreads();
    cur[threadIdx.x] = excl;
    __syncthreads();

    for (int e = beg + threadIdx.x; e < end; e += blockDim.x) {
        unsigned pk = staged[e];
        int l = (int)(pk >> 23);
        int p = atomicAdd(&cur[l], 1);          // LDS atomic only
        col[beg + p] = (int)(pk & 0x7FFFFF);
    }
}

// ---------------------------------------------------------------------------
// Vector row load: float4 chunks, then float2, then scalar.
template<int CI>
__device__ __forceinline__ void load_row(const float* __restrict__ p, float* r) {
    constexpr int N4 = CI / 4;
#pragma unroll
    for (int i = 0; i < N4; i++) {
        float4 v = ((const float4*)p)[i];
        r[4*i] = v.x; r[4*i+1] = v.y; r[4*i+2] = v.z; r[4*i+3] = v.w;
    }
    if constexpr ((CI % 4) >= 2) {
        float2 v = ((const float2*)(p + 4 * N4))[0];
        r[4*N4] = v.x; r[4*N4+1] = v.y;
    }
    if constexpr ((CI % 2) == 1) r[CI - 1] = p[CI - 1];
}

// ---------------------------------------------------------------------------
// Fused layer, lane-group parallel (G lanes/node), 4-deep gather pipeline,
// LDS weights padded to CI+1 to break power-of-2 bank aliasing.
template<int CI, int SI, int CO, int SO, int G, bool IN_AFFINE, bool DO_STATS>
__global__ void layer_kernel(const int* __restrict__ row_ptr, const int* __restrict__ col,
                             const float* __restrict__ h,
                             const float* __restrict__ ssum_in, const float* __restrict__ ssq_in,
                             const float* __restrict__ g_in, const float* __restrict__ b_in,
                             const float* __restrict__ wl, const float* __restrict__ bl,
                             const float* __restrict__ wr,
                             float* __restrict__ y,
                             float* __restrict__ stat_sum, float* __restrict__ stat_sq) {
    constexpr int NPB = 256 / G;             // nodes per block
    constexpr int OPL = (CO + G - 1) / G;    // outputs per lane
    constexpr int PCI = CI + 1;              // padded LDS stride (bank-conflict fix)

    __shared__ float sWl[CO * PCI];
    __shared__ float sWr[CO * PCI];
    __shared__ float sBl[CO];
    __shared__ float sSc[CI];
    __shared__ float sSh[CI];
    __shared__ float red_sum[CO];
    __shared__ float red_sq[CO];

    for (int i = threadIdx.x; i < CO * CI; i += blockDim.x) {
        int o = i / CI, c = i - o * CI;
        sWl[o * PCI + c] = wl[i];
        sWr[o * PCI + c] = wr[i];
    }
    if (threadIdx.x < CO) {
        sBl[threadIdx.x] = bl[threadIdx.x];
        if (DO_STATS) { red_sum[threadIdx.x] = 0.0f; red_sq[threadIdx.x] = 0.0f; }
    }
    if (IN_AFFINE && threadIdx.x < CI) {
        float m  = ssum_in[threadIdx.x] * (1.0f / NNODES);
        float vv = ssq_in[threadIdx.x] * (1.0f / NNODES) - m * m;
        float s  = g_in[threadIdx.x] / sqrtf(vv + BN_EPS);
        sSc[threadIdx.x] = s;
        sSh[threadIdx.x] = b_in[threadIdx.x] - m * s;
    }
    __syncthreads();

    int node = blockIdx.x * NPB + (threadIdx.x / G);
    int g    = threadIdx.x & (G - 1);
    bool valid = node < NNODES;

    float acc[CI];
#pragma unroll
    for (int c = 0; c < CI; c++) acc[c] = 0.0f;

    int beg = 0, end = 0;
    if (valid) {
        beg = row_ptr[node];
        end = row_ptr[node + 1];
        int j = beg + g;
        // 4 rows in flight
        for (; j + 3 * G < end; j += 4 * G) {
            int i0 = col[j], i1 = col[j + G], i2 = col[j + 2 * G], i3 = col[j + 3 * G];
            float r0[CI], r1[CI], r2[CI], r3[CI];
            load_row<CI>(h + (long)i0 * SI, r0);
            load_row<CI>(h + (long)i1 * SI, r1);
            load_row<CI>(h + (long)i2 * SI, r2);
            load_row<CI>(h + (long)i3 * SI, r3);
#pragma unroll
            for (int c = 0; c < CI; c++) acc[c] += (r0[c] + r1[c]) + (r2[c] + r3[c]);
        }
        // 2 rows in flight
        for (; j + G < end; j += 2 * G) {
            int i0 = col[j], i1 = col[j + G];
            float r0[CI], r1[CI];
            load_row<CI>(h + (long)i0 * SI, r0);
            load_row<CI>(h + (long)i1 * SI, r1);
#pragma unroll
            for (int c = 0; c < CI; c++) acc[c] += r0[c] + r1[c];
        }
        if (j < end) {
            float r0[CI];
            load_row<CI>(h + (long)col[j] * SI, r0);
#pragma unroll
            for (int c = 0; c < CI; c++) acc[c] += r0[c];
        }
    }

    // butterfly: all G lanes end with the full neighbor sum
#pragma unroll
    for (int m = 1; m < G; m <<= 1)
#pragma unroll
        for (int c = 0; c < CI; c++) acc[c] += __shfl_xor(acc[c], m);

    float out[OPL];
    float nrm2 = 0.0f;
    if (valid) {
        float ic = 1.0f / fmaxf((float)(end - beg), 1.0f);
        float xin[CI];
        load_row<CI>(h + (long)node * SI, xin);
        float agg[CI];
#pragma unroll
        for (int c = 0; c < CI; c++) {
            float a  = acc[c] * ic;
            float xv = xin[c];
            if (IN_AFFINE) {
                a  = a  * sSc[c] + sSh[c];
                xv = xv * sSc[c] + sSh[c];
            }
            agg[c] = a;
            xin[c] = xv;
        }
#pragma unroll
        for (int k = 0; k < OPL; k++) {
            int o = g * OPL + k;
            float v = 0.0f;
            if (o < CO) {
                v = sBl[o];
#pragma unroll
                for (int c = 0; c < CI; c++)
                    v += sWl[o * PCI + c] * agg[c] + sWr[o * PCI + c] * xin[c];
            }
            out[k] = v;
            nrm2 += v * v;
        }
    }
#pragma unroll
    for (int m = 1; m < G; m <<= 1) nrm2 += __shfl_xor(nrm2, m);

    if (valid) {
        float inv_nrm = 1.0f / fmaxf(sqrtf(nrm2), L2_EPS);
#pragma unroll
        for (int k = 0; k < OPL; k++) {
            int o = g * OPL + k;
            if (o < CO) {
                float v = fmaxf(out[k] * inv_nrm, 0.0f);   // L2 norm + ReLU
                y[(long)node * SO + o] = v;
                if (DO_STATS) {
                    atomicAdd(&red_sum[o], v);
                    atomicAdd(&red_sq[o], v * v);
                }
            }
        }
    }

    if (DO_STATS) {
        __syncthreads();
        if (threadIdx.x < CO) {
            atomicAdd(&stat_sum[threadIdx.x], red_sum[threadIdx.x]);
            atomicAdd(&stat_sq[threadIdx.x], red_sq[threadIdx.x]);
        }
    }
}

// ---------------------------------------------------------------------------
extern "C" void kernel_launch(void* const* d_in, const int* in_sizes, int n_in,
                              void* d_out, int out_size, void* d_ws, size_t ws_size,
                              hipStream_t stream) {
    const float* x   = (const float*)d_in[0];
    const int*   ei  = (const int*)d_in[1];
    const int*   src = ei;
    const int*   dst = ei + NEDGES;

    const float* w1l = (const float*)d_in[2];
    const float* b1l = (const float*)d_in[3];
    const float* w1r = (const float*)d_in[4];
    const float* w2l = (const float*)d_in[5];
    const float* b2l = (const float*)d_in[6];
    const float* w2r = (const float*)d_in[7];
    const float* w3l = (const float*)d_in[8];
    const float* b3l = (const float*)d_in[9];
    const float* w3r = (const float*)d_in[10];
    const float* w4l = (const float*)d_in[11];
    const float* b4l = (const float*)d_in[12];
    const float* w4r = (const float*)d_in[13];
    const float* g1  = (const float*)d_in[14];
    const float* be1 = (const float*)d_in[15];
    const float* g2  = (const float*)d_in[16];
    const float* be2 = (const float*)d_in[17];
    const float* g3  = (const float*)d_in[18];
    const float* be3 = (const float*)d_in[19];

    char* w = (char*)d_ws;
    int* blk_hist     = (int*)w;  w += NBLK_E * NBKT * 4;
    int* blk_off      = (int*)w;  w += NBLK_E * NBKT * 4;
    int* bucket_total = (int*)w;  w += 256 * 4;
    int* bucket_base  = (int*)w;  w += 256 * 4;
    int* row_ptr      = (int*)w;  w += (NNODES + 8) * 4;
    int* col          = (int*)w;  w += NEDGES * 4;
    float* hA         = (float*)w; w += NNODES * 16 * 4;
    float* hB         = (float*)w; w += NNODES * 16 * 4;   // aliased by staged
    float* stats      = (float*)w; w += 3 * 128 * 4;
    unsigned int* staged = (unsigned int*)hB;  // dead before hB is written

    float* ssum1 = stats + 0 * 128, *ssq1 = ssum1 + 32;
    float* ssum2 = stats + 1 * 128, *ssq2 = ssum2 + 32;
    float* ssum3 = stats + 2 * 128, *ssq3 = ssum3 + 32;

    // atomic-free CSR build
    hist_kernel   <<<NBLK_E, 256, 0, stream>>>(dst, blk_hist, stats);
    scan_blocks   <<<NBKT, 512, 0, stream>>>(blk_hist, blk_off, bucket_total);
    scan_buckets  <<<1, 256, 0, stream>>>(bucket_total, bucket_base);
    bucket_scatter<<<NBLK_E, 256, 0, stream>>>(src, dst, blk_off, bucket_base, staged);
    csr_finalize  <<<NBKT, 512, 0, stream>>>(staged, bucket_base, row_ptr, col);

    // layer 1: 4 -> 6 (stride 4 -> 8), G=4, +stats
    layer_kernel<4, 4, 6, 8, 4, false, true><<<(NNODES * 4 + 255) / 256, 256, 0, stream>>>(
        row_ptr, col, x, nullptr, nullptr, nullptr, nullptr,
        w1l, b1l, w1r, hA, ssum1, ssq1);

    // layer 2: 6 -> 8 (stride 8 -> 8), G=4, BN1 derived in-block, +stats
    layer_kernel<6, 8, 8, 8, 4, true, true><<<(NNODES * 4 + 255) / 256, 256, 0, stream>>>(
        row_ptr, col, hA, ssum1, ssq1, g1, be1,
        w2l, b2l, w2r, hB, ssum2, ssq2);

    // layer 3: 8 -> 16 (stride 8 -> 16), G=4, BN2 derived, +stats
    layer_kernel<8, 8, 16, 16, 4, true, true><<<(NNODES * 4 + 255) / 256, 256, 0, stream>>>(
        row_ptr, col, hB, ssum2, ssq2, g2, be2,
        w3l, b3l, w3r, hA, ssum3, ssq3);

    // layer 4: 16 -> 32 (stride 16 -> 32), G=8, BN3 derived, ReLU -> d_out
    layer_kernel<16, 16, 32, 32, 8, true, false><<<(NNODES * 8 + 255) / 256, 256, 0, stream>>>(
        row_ptr, col, hA, ssum3, ssq3, g3, be3,
        w4l, b4l, w4r, (float*)d_out, nullptr, nullptr);
}